// Round 3
// baseline (363.406 us; speedup 1.0000x reference)
//
#include <hip/hip_runtime.h>
#include <stdint.h>

// Problem dims (fixed by reference)
#define B_ 8
#define T_ 1024
#define E_ 1024
#define H_ 16
#define S_ 64

typedef __attribute__((ext_vector_type(8))) short bf16x8;   // 8 bf16 in 4 VGPRs
typedef __attribute__((ext_vector_type(4))) float f32x4;

__device__ __forceinline__ ushort f2bf(float f) {
  union { float f; uint32_t u; } v; v.f = f;
  uint32_t r = (v.u + 0x7FFFu + ((v.u >> 16) & 1u)) >> 16;  // RNE
  return (ushort)r;
}
__device__ __forceinline__ float bf2f(ushort u) {
  union { uint32_t u; float f; } v; v.u = ((uint32_t)u) << 16;
  return v.f;
}

// 8 contiguous elements starting at element index idx; src may be fp32 or bf16.
__device__ __forceinline__ bf16x8 load8(const void* p, size_t idx, bool isf32) {
  if (isf32) {
    const float* fp = (const float*)p + idx;
    f32x4 f0 = *(const f32x4*)(fp);
    f32x4 f1 = *(const f32x4*)(fp + 4);
    bf16x8 r;
    #pragma unroll
    for (int i = 0; i < 4; ++i) r[i] = (short)f2bf(f0[i]);
    #pragma unroll
    for (int i = 0; i < 4; ++i) r[4 + i] = (short)f2bf(f1[i]);
    return r;
  }
  return *(const bf16x8*)((const ushort*)p + idx);
}

__device__ __forceinline__ float load1(const void* p, size_t idx, bool isf32) {
  return isf32 ? ((const float*)p)[idx] : bf2f(((const ushort*)p)[idx]);
}

// ---------------------------------------------------------------------------
// Kernel 0: detect input dtype. Low 16 bits of each 32b word: sane bf16 if
// data is bf16; fp32 mantissa garbage (uniform exponent) if data is fp32.
// ---------------------------------------------------------------------------
__global__ void detect_kernel(const uint32_t* __restrict__ x, int* __restrict__ flag) {
  if (threadIdx.x == 0 && blockIdx.x == 0) {
    int sane = 0;
    for (int i = 0; i < 256; ++i) {
      uint32_t lo = x[i] & 0xFFFFu;
      uint32_t e = (lo >> 7) & 0xFFu;
      if (e >= 96u && e <= 158u) ++sane;
    }
    *flag = (sane < 192) ? 1 : 0;   // 1 = fp32 inputs, 0 = bf16 inputs
  }
}

// ---------------------------------------------------------------------------
// Kernel 1: Q/K/V projection.  rows = B*T*H (each row = 64 elems of x),
// y = x_row @ W^T for W in {Wq,Wk,Wv}.  Output (bf16) layout [b][h][t][s].
// MFMA 16x16x32 bf16: A[m=lane&15][k=quad*8+j], B[k=quad*8+j][n=lane&15],
// D: col=lane&15, row=quad*4+reg.
// ---------------------------------------------------------------------------
__global__ __launch_bounds__(256) void qkv_kernel(
    const void* __restrict__ x,
    const void* __restrict__ Wq, const void* __restrict__ Wk,
    const void* __restrict__ Wv, const int* __restrict__ flag,
    ushort* __restrict__ qb, ushort* __restrict__ kb, ushort* __restrict__ vb) {
  const bool f32 = (*flag != 0);
  const int lane = threadIdx.x & 63;
  const int wave = threadIdx.x >> 6;
  const int m = lane & 15, quad = lane >> 4;
  const int r0 = blockIdx.x * 64 + wave * 16;        // 16 rows per wave

  const size_t xbase = (size_t)(r0 + m) * S_;
  bf16x8 a0 = load8(x, xbase + quad * 8, f32);
  bf16x8 a1 = load8(x, xbase + 32 + quad * 8, f32);

  const void* Ws[3] = {Wq, Wk, Wv};
  ushort* Ob[3] = {qb, kb, vb};

  #pragma unroll
  for (int w = 0; w < 3; ++w) {
    #pragma unroll
    for (int nt = 0; nt < 4; ++nt) {
      const size_t wbase = (size_t)(nt * 16 + m) * S_;
      bf16x8 b0 = load8(Ws[w], wbase + quad * 8, f32);
      bf16x8 b1 = load8(Ws[w], wbase + 32 + quad * 8, f32);
      f32x4 acc = {0.f, 0.f, 0.f, 0.f};
      acc = __builtin_amdgcn_mfma_f32_16x16x32_bf16(a0, b0, acc, 0, 0, 0);
      acc = __builtin_amdgcn_mfma_f32_16x16x32_bf16(a1, b1, acc, 0, 0, 0);
      #pragma unroll
      for (int i = 0; i < 4; ++i) {
        int r = r0 + quad * 4 + i;          // r = b*16384 + t*16 + h
        int bb = r >> 14;
        int tt = (r >> 4) & 1023;
        int hh = r & 15;
        size_t off = (((size_t)bb * H_ + hh) * T_ + tt) * S_ + nt * 16 + m;
        Ob[w][off] = f2bf(acc[i]);
      }
    }
  }
}

// ---------------------------------------------------------------------------
// Kernel 2: causal flash attention per (b,h,q-tile of 64).  4 waves x 16 rows.
// scores scaled by E^-0.5 = 1/32 (reference scales q,k by E^-0.25 each).
// ---------------------------------------------------------------------------
__global__ __launch_bounds__(256) void attn_kernel(
    const ushort* __restrict__ qb, const ushort* __restrict__ kb,
    const ushort* __restrict__ vb, const int* __restrict__ lengths,
    ushort* __restrict__ ao) {
  __shared__ ushort vt[64 * 72];        // V^T tile: vt[vo][k], stride 72
  __shared__ ushort pbuf[4 * 16 * 72];  // per-wave P tile (16 q x 64 k)

  const int tid = threadIdx.x;
  const int lane = tid & 63, wave = tid >> 6;
  const int m = lane & 15, quad = lane >> 4;
  const int qt = blockIdx.x & 15;
  const int h  = (blockIdx.x >> 4) & 15;
  const int b  = blockIdx.x >> 8;
  const int len = lengths[b];

  const size_t head_off = ((size_t)b * H_ + h) * (size_t)T_ * S_;
  const ushort* Q = qb + head_off;
  const ushort* K = kb + head_off;
  const ushort* V = vb + head_off;

  const int qw0 = qt * 64 + wave * 16;  // this wave's first q row
  bf16x8 aq0 = *(const bf16x8*)(Q + (size_t)(qw0 + m) * S_ + quad * 8);
  bf16x8 aq1 = *(const bf16x8*)(Q + (size_t)(qw0 + m) * S_ + 32 + quad * 8);

  f32x4 o[4];
  float Mx[4], L[4];
  #pragma unroll
  for (int i = 0; i < 4; ++i) { o[i] = (f32x4){0.f,0.f,0.f,0.f}; Mx[i] = -1e30f; L[i] = 0.f; }

  ushort* pw = pbuf + wave * (16 * 72);

  for (int kt = 0; kt <= qt; ++kt) {
    __syncthreads();   // protect vt from previous iteration's reads
    // stage V^T into LDS (4096 elems, 256 threads x 2 chunks of 8)
    #pragma unroll
    for (int p = 0; p < 2; ++p) {
      int c = tid + p * 256;
      int kr = c >> 3;
      int vo0 = (c & 7) * 8;
      bf16x8 vv = *(const bf16x8*)(V + (size_t)(kt * 64 + kr) * S_ + vo0);
      #pragma unroll
      for (int j = 0; j < 8; ++j) vt[(vo0 + j) * 72 + kr] = (ushort)vv[j];
    }

    // S = Q K^T for this wave's 16 q rows x 64 keys
    float sv[4][4];
    #pragma unroll
    for (int nt = 0; nt < 4; ++nt) {
      const ushort* krow = K + (size_t)(kt * 64 + nt * 16 + m) * S_;
      bf16x8 bk0 = *(const bf16x8*)(krow + quad * 8);
      bf16x8 bk1 = *(const bf16x8*)(krow + 32 + quad * 8);
      f32x4 s = {0.f,0.f,0.f,0.f};
      s = __builtin_amdgcn_mfma_f32_16x16x32_bf16(aq0, bk0, s, 0, 0, 0);
      s = __builtin_amdgcn_mfma_f32_16x16x32_bf16(aq1, bk1, s, 0, 0, 0);
      const int key = kt * 64 + nt * 16 + m;   // col index = lane&15
      #pragma unroll
      for (int i = 0; i < 4; ++i) {
        int qrow = qw0 + quad * 4 + i;
        // clamp: NaN -> -1e30 (fmaxf picks non-NaN), inf -> 1e30
        float raw = fminf(fmaxf(s[i] * 0.03125f, -1e30f), 1e30f);
        sv[nt][i] = (key <= qrow && key < len) ? raw : -1e30f;
      }
    }

    // online softmax (rows live on 16-lane groups; reduce with shfl_xor width 16)
    float rmax[4];
    #pragma unroll
    for (int i = 0; i < 4; ++i)
      rmax[i] = fmaxf(fmaxf(sv[0][i], sv[1][i]), fmaxf(sv[2][i], sv[3][i]));
    #pragma unroll
    for (int off = 8; off >= 1; off >>= 1) {
      #pragma unroll
      for (int i = 0; i < 4; ++i)
        rmax[i] = fmaxf(rmax[i], __shfl_xor(rmax[i], off, 16));
    }
    float alpha[4];
    #pragma unroll
    for (int i = 0; i < 4; ++i) {
      float mn = fmaxf(Mx[i], rmax[i]);
      alpha[i] = __expf(Mx[i] - mn);     // (-1e30)-(-1e30)=0 -> alpha=1, safe
      Mx[i] = mn;
    }
    float pv[4][4], rsum[4];
    #pragma unroll
    for (int nt = 0; nt < 4; ++nt)
      #pragma unroll
      for (int i = 0; i < 4; ++i)
        pv[nt][i] = (sv[nt][i] <= -1e29f) ? 0.f : __expf(sv[nt][i] - Mx[i]);
    #pragma unroll
    for (int i = 0; i < 4; ++i)
      rsum[i] = pv[0][i] + pv[1][i] + pv[2][i] + pv[3][i];
    #pragma unroll
    for (int off = 8; off >= 1; off >>= 1) {
      #pragma unroll
      for (int i = 0; i < 4; ++i)
        rsum[i] += __shfl_xor(rsum[i], off, 16);
    }
    #pragma unroll
    for (int i = 0; i < 4; ++i) L[i] = L[i] * alpha[i] + rsum[i];
    #pragma unroll
    for (int v4 = 0; v4 < 4; ++v4)
      #pragma unroll
      for (int i = 0; i < 4; ++i)
        o[v4][i] *= alpha[i];

    // P (C-layout) -> LDS -> A-layout fragments
    #pragma unroll
    for (int nt = 0; nt < 4; ++nt)
      #pragma unroll
      for (int i = 0; i < 4; ++i)
        pw[(quad * 4 + i) * 72 + nt * 16 + m] = f2bf(pv[nt][i]);
    __syncthreads();   // orders P write->read and vt write->read

    bf16x8 ap0 = *(const bf16x8*)(pw + m * 72 + quad * 8);
    bf16x8 ap1 = *(const bf16x8*)(pw + m * 72 + 32 + quad * 8);
    #pragma unroll
    for (int v4 = 0; v4 < 4; ++v4) {
      const ushort* vr = vt + (v4 * 16 + m) * 72;
      bf16x8 bv0 = *(const bf16x8*)(vr + quad * 8);
      bf16x8 bv1 = *(const bf16x8*)(vr + 32 + quad * 8);
      o[v4] = __builtin_amdgcn_mfma_f32_16x16x32_bf16(ap0, bv0, o[v4], 0, 0, 0);
      o[v4] = __builtin_amdgcn_mfma_f32_16x16x32_bf16(ap1, bv1, o[v4], 0, 0, 0);
    }
  }

  // epilogue: O/L -> att_out [b][t][e]
  #pragma unroll
  for (int i = 0; i < 4; ++i) {
    float inv = (L[i] > 0.f) ? 1.0f / L[i] : 0.f;
    int qrow = qw0 + quad * 4 + i;
    size_t base = ((size_t)b * T_ + qrow) * E_ + h * 64;
    #pragma unroll
    for (int v4 = 0; v4 < 4; ++v4)
      ao[base + v4 * 16 + m] = f2bf(o[v4][i] * inv);
  }
}

// ---------------------------------------------------------------------------
// Kernel 3: Y = att @ Wu^T + bu.  M=8192, N=1024, K=1024.  Output fp32.
// 128x128 tile per block, 4 waves in 2x2 (64x64 each), BK=64 LDS staging.
// ---------------------------------------------------------------------------
__global__ __launch_bounds__(256) void proj_kernel(
    const ushort* __restrict__ A, const void* __restrict__ Wu,
    const void* __restrict__ bu, const int* __restrict__ flag,
    float* __restrict__ Y) {
  __shared__ ushort As[128 * 72];
  __shared__ ushort Bs[128 * 72];
  const bool f32 = (*flag != 0);
  const int tid = threadIdx.x;
  const int lane = tid & 63, wave = tid >> 6;
  const int m = lane & 15, quad = lane >> 4;
  const int m0 = blockIdx.x * 128, n0 = blockIdx.y * 128;
  const int wm = (wave & 1) * 64, wn = (wave >> 1) * 64;

  f32x4 acc[4][4];
  #pragma unroll
  for (int i = 0; i < 4; ++i)
    #pragma unroll
    for (int j = 0; j < 4; ++j) acc[i][j] = (f32x4){0.f,0.f,0.f,0.f};

  for (int k0 = 0; k0 < E_; k0 += 64) {
    __syncthreads();
    #pragma unroll
    for (int p = 0; p < 4; ++p) {
      int c = tid + p * 256;
      int row = c >> 3, col = (c & 7) * 8;
      *(bf16x8*)(As + row * 72 + col) = *(const bf16x8*)(A + (size_t)(m0 + row) * E_ + k0 + col);
      *(bf16x8*)(Bs + row * 72 + col) = load8(Wu, (size_t)(n0 + row) * E_ + k0 + col, f32);
    }
    __syncthreads();
    #pragma unroll
    for (int kk = 0; kk < 64; kk += 32) {
      bf16x8 af[4], bfrag[4];
      #pragma unroll
      for (int i = 0; i < 4; ++i)
        af[i] = *(const bf16x8*)(As + (wm + i * 16 + m) * 72 + kk + quad * 8);
      #pragma unroll
      for (int j = 0; j < 4; ++j)
        bfrag[j] = *(const bf16x8*)(Bs + (wn + j * 16 + m) * 72 + kk + quad * 8);
      #pragma unroll
      for (int i = 0; i < 4; ++i)
        #pragma unroll
        for (int j = 0; j < 4; ++j)
          acc[i][j] = __builtin_amdgcn_mfma_f32_16x16x32_bf16(af[i], bfrag[j], acc[i][j], 0, 0, 0);
    }
  }

  #pragma unroll
  for (int j = 0; j < 4; ++j) {
    float bias = load1(bu, n0 + wn + j * 16 + m, f32);
    #pragma unroll
    for (int i = 0; i < 4; ++i) {
      #pragma unroll
      for (int r = 0; r < 4; ++r) {
        int grow = m0 + wm + i * 16 + quad * 4 + r;
        int gcol = n0 + wn + j * 16 + m;
        Y[(size_t)grow * E_ + gcol] = acc[i][j][r] + bias;   // fp32 output
      }
    }
  }
}

// ---------------------------------------------------------------------------
extern "C" void kernel_launch(void* const* d_in, const int* in_sizes, int n_in,
                              void* d_out, int out_size, void* d_ws, size_t ws_size,
                              hipStream_t stream) {
  // setup_inputs order: x, lengths, Wk, Wq, Wv, Wu, bu
  const void* x  = d_in[0];
  const int* lengths = (const int*)d_in[1];
  const void* Wk = d_in[2];
  const void* Wq = d_in[3];
  const void* Wv = d_in[4];
  const void* Wu = d_in[5];
  const void* bu = d_in[6];
  float* out = (float*)d_out;

  // workspace: Q,K,V bf16 in [b][h][t][s] + att_out bf16 in [b][t][e] + flag
  const size_t hsz = (size_t)B_ * H_ * T_ * S_;
  ushort* qb = (ushort*)d_ws;
  ushort* kb = qb + hsz;
  ushort* vb = kb + hsz;
  ushort* ao = vb + hsz;
  int* flag  = (int*)(ao + hsz);

  detect_kernel<<<dim3(1), dim3(64), 0, stream>>>((const uint32_t*)x, flag);
  qkv_kernel<<<dim3((B_ * T_ * H_) / 64), dim3(256), 0, stream>>>(x, Wq, Wk, Wv, flag, qb, kb, vb);
  attn_kernel<<<dim3(B_ * H_ * (T_ / 64)), dim3(256), 0, stream>>>(qb, kb, vb, lengths, ao);
  proj_kernel<<<dim3((B_ * T_) / 128, E_ / 128), dim3(256), 0, stream>>>(ao, Wu, bu, flag, out);
}